// Round 7
// baseline (253.679 us; speedup 1.0000x reference)
//
#include <hip/hip_runtime.h>

#define NJ  21
#define FT  6
#define TRS 43   // output tile row stride (floats); odd -> bank-conflict-free
#define WRS 12   // weight row stride: 10 floats padded to 12 (48B, 16B-aligned)

// One thread per batch element; joints in index order (parent < child).
// Rounds 2-6 lesson: stall is NOT writes (fixed r5, neutral), NOT weight path
// (SMEM r2-4 vs LDS r6 identical ~25-30% VALU). Model: per-joint quat load
// (global, ~500-900cy miss) feeds the joint's first fmaf with only ~350cy of
// compute per joint and 3.35 waves/SIMD -> exposed latency, VALUBusy ~1/3.3.
// Fix this round: prefetch quats ONE CHUNK AHEAD into named float4 registers
// (VGPRs 64->128 are free: LDS caps occupancy at 4 blocks/CU either way).

#define F10(W, Bv, a0,a1,a2,a3,a4,a5,a6,a7,a8,a9) \
  fmaxf(fmaf((W)[9],(a9),fmaf((W)[8],(a8),fmaf((W)[7],(a7),fmaf((W)[6],(a6), \
        fmaf((W)[5],(a5),fmaf((W)[4],(a4),fmaf((W)[3],(a3),fmaf((W)[2],(a2), \
        fmaf((W)[1],(a1),fmaf((W)[0],(a0),(Bv))))))))))), 0.0f)

#define HROW(N,P,j,r) const float h##N##_##r = \
  F10(w1s + ((j)-1)*10*WRS + (r)*WRS, b1s[((j)-1)*10 + (r)], \
      q##N.x, q##N.y, q##N.z, q##N.w, \
      f##P##_0, f##P##_1, f##P##_2, f##P##_3, f##P##_4, f##P##_5);

#define FROW(N,j,r) const float f##N##_##r = \
  F10(w2s + (j)*6*WRS + (r)*WRS, b2s[(j)*6 + (r)], \
      h##N##_0, h##N##_1, h##N##_2, h##N##_3, h##N##_4, \
      h##N##_5, h##N##_6, h##N##_7, h##N##_8, h##N##_9);

#define LOADQ(N,j) const float4 q##N = qv[j];

// qN must already be loaded (prefetched a chunk ahead)
#define DO_JOINT(j,P,N) \
  HROW(N,P,j,0) HROW(N,P,j,1) HROW(N,P,j,2) HROW(N,P,j,3) HROW(N,P,j,4) \
  HROW(N,P,j,5) HROW(N,P,j,6) HROW(N,P,j,7) HROW(N,P,j,8) HROW(N,P,j,9) \
  FROW(N,j,0) FROW(N,j,1) FROW(N,j,2) FROW(N,j,3) FROW(N,j,4) FROW(N,j,5)

#define PUT6(p, N) { (p)[0]=f##N##_0; (p)[1]=f##N##_1; (p)[2]=f##N##_2; \
                     (p)[3]=f##N##_3; (p)[4]=f##N##_4; (p)[5]=f##N##_5; }

#define HALF_FLUSH(k, half, N0,N1,N2,N3,N4,N5,N6) \
  __syncthreads(); \
  if ((tid >> 7) == (half)) { \
    float* tr_ = tile + (tid & 127) * TRS; \
    PUT6(tr_+0,  N0) PUT6(tr_+6,  N1) PUT6(tr_+12, N2) PUT6(tr_+18, N3) \
    PUT6(tr_+24, N4) PUT6(tr_+30, N5) PUT6(tr_+36, N6) \
  } \
  __syncthreads(); \
  { const int lane_ = tid & 63, w_ = tid >> 6; \
    _Pragma("unroll") \
    for (int i_ = 0; i_ < 21; ++i_) { \
      const int idx_ = w_ * 1344 + i_ * 64 + lane_; \
      const int row_ = idx_ / 42, col_ = idx_ - row_ * 42; \
      const int rg_  = base + (half)*128 + row_; \
      if (rg_ < B) out[(size_t)rg_ * 126 + (k)*42 + col_] = tile[row_ * TRS + col_]; \
    } \
  }

#define CHUNK_FLUSH(k, N0,N1,N2,N3,N4,N5,N6) \
  HALF_FLUSH(k, 0, N0,N1,N2,N3,N4,N5,N6) \
  HALF_FLUSH(k, 1, N0,N1,N2,N3,N4,N5,N6)

__global__ __launch_bounds__(256, 4) void se_kernel(
    const float* __restrict__ quat,   // [B, 21, 4]
    const float* __restrict__ W1r,    // [10, 4]
    const float* __restrict__ b1r,    // [10]
    const float* __restrict__ W1,     // [20, 10, 10]
    const float* __restrict__ b1,     // [20, 10]
    const float* __restrict__ W2,     // [21, 6, 10]
    const float* __restrict__ b2,     // [21, 6]
    float*       __restrict__ out,    // [B, 126]
    int B)
{
    __shared__ __align__(16) float w1s[20*10*WRS];   // 9600 B
    __shared__ __align__(16) float w2s[21*6*WRS];    // 6048 B
    __shared__ float b1s[200], b2s[126], w1rs[40], b1rs[16];
    __shared__ float tile[128*TRS];                  // 22016 B -> ~39 KB total

    const int tid  = threadIdx.x;
    const int base = blockIdx.x * 256;

    // ---- stage weights into LDS (once per block) ----
    for (int i = tid; i < 2000; i += 256) w1s[(i/10)*WRS + i%10] = W1[i];
    for (int i = tid; i < 1260; i += 256) w2s[(i/10)*WRS + i%10] = W2[i];
    for (int i = tid; i < 200;  i += 256) b1s[i] = b1[i];
    if (tid < 126) b2s[tid] = b2[tid];
    if (tid < 40)  w1rs[tid] = W1r[tid];
    if (tid < 10)  b1rs[tid] = b1r[tid];
    __syncthreads();

    const int bcl = min(base + tid, B - 1);
    const float4* __restrict__ qv =
        reinterpret_cast<const float4*>(quat) + (size_t)bcl * NJ;

    // ---- prefetch: chunk0 + chunk1 quats issued up front ----
    LOADQ(0,0)   LOADQ(1,1)   LOADQ(2,2)   LOADQ(3,3)
    LOADQ(4,4)   LOADQ(5,5)   LOADQ(6,6)
    LOADQ(7,7)   LOADQ(8,8)   LOADQ(9,9)   LOADQ(10,10)
    LOADQ(11,11) LOADQ(12,12) LOADQ(13,13)

    // ---- chunk 0: joints 0..6 ----
#define H0ROW(r) const float h0_##r = fmaxf( \
    fmaf(w1rs[(r)*4+3], q0.w, fmaf(w1rs[(r)*4+2], q0.z, \
    fmaf(w1rs[(r)*4+1], q0.y, fmaf(w1rs[(r)*4+0], q0.x, b1rs[r])))), 0.0f);
    H0ROW(0) H0ROW(1) H0ROW(2) H0ROW(3) H0ROW(4)
    H0ROW(5) H0ROW(6) H0ROW(7) H0ROW(8) H0ROW(9)
#undef H0ROW
    FROW(0,0,0) FROW(0,0,1) FROW(0,0,2) FROW(0,0,3) FROW(0,0,4) FROW(0,0,5)

    DO_JOINT(1,0,1)  DO_JOINT(2,0,2)  DO_JOINT(3,0,3)
    DO_JOINT(4,1,4)  DO_JOINT(5,2,5)  DO_JOINT(6,3,6)

    // prefetch chunk2 quats before the flush (latency hides under flush+chunk1)
    LOADQ(14,14) LOADQ(15,15) LOADQ(16,16) LOADQ(17,17)
    LOADQ(18,18) LOADQ(19,19) LOADQ(20,20)

    CHUNK_FLUSH(0, 0,1,2,3,4,5,6)

    // ---- chunk 1: joints 7..13 ----
    DO_JOINT(7,4,7)   DO_JOINT(8,5,8)   DO_JOINT(9,6,9)
    DO_JOINT(10,7,10) DO_JOINT(11,8,11)
    DO_JOINT(12,9,12) DO_JOINT(13,9,13)
    CHUNK_FLUSH(1, 7,8,9,10,11,12,13)

    // ---- chunk 2: joints 14..20 ----
    DO_JOINT(14,9,14)  DO_JOINT(15,12,15) DO_JOINT(16,13,16)
    DO_JOINT(17,14,17) DO_JOINT(18,16,18)
    DO_JOINT(19,17,19) DO_JOINT(20,18,20)
    CHUNK_FLUSH(2, 14,15,16,17,18,19,20)
}

extern "C" void kernel_launch(void* const* d_in, const int* in_sizes, int n_in,
                              void* d_out, int out_size, void* d_ws, size_t ws_size,
                              hipStream_t stream) {
    const float* quat = (const float*)d_in[0];
    const float* W1r  = (const float*)d_in[1];
    const float* b1r  = (const float*)d_in[2];
    const float* W1   = (const float*)d_in[3];
    const float* b1   = (const float*)d_in[4];
    const float* W2   = (const float*)d_in[5];
    const float* b2   = (const float*)d_in[6];
    float* out = (float*)d_out;

    const int B = in_sizes[0] / (NJ * 4);
    const int threads = 256;
    const int blocks  = (B + threads - 1) / threads;
    se_kernel<<<blocks, threads, 0, stream>>>(quat, W1r, b1r, W1, b1, W2, b2, out, B);
}